// Round 3
// baseline (268.407 us; speedup 1.0000x reference)
//
#include <hip/hip_runtime.h>

// x: (64, 64, 128, 128) f32; weight: (64, 128, 3, 3) f32; bias: (128,) f32
// out: (64, 128, 1, 1) f32
// stats[b][c][j], j in {full, top(row0), left(col0), corner}
// out[b][o] = 2*bias[o] + (2/65536) * sum_{c,j} stats[b][c][j]*coeff[o][c][j]
//
// Single fused kernel: 4096 blocks compute stats; the last 64 blocks to
// finish (agent-scope atomic counter) each take one b-row, spin until all
// stats are published, and compute that row's 128 outputs.

typedef float fvec4 __attribute__((ext_vector_type(4)));

static constexpr int NBLK = 4096;
static constexpr int NEPI = 64;   // epilogue blocks (one per b)

__global__ __launch_bounds__(256) void fused_kernel(const float* __restrict__ x,
                                                    const float* __restrict__ weight,
                                                    const float* __restrict__ bias,
                                                    float* __restrict__ out,
                                                    float* __restrict__ stats,
                                                    unsigned int* __restrict__ counter) {
    const int bc = blockIdx.x;            // b*64 + c
    const int tid = threadIdx.x;
    const fvec4* img = reinterpret_cast<const fvec4*>(x) + (size_t)bc * 4096;

    // ---- phase 1: per-image stats, branch-free main loop ----
    float s_full, s_top = 0.f, s_leftraw, s_corner = 0.f;
    {   // iteration 0 contains row 0 (float4 index < 32)
        fvec4 v = __builtin_nontemporal_load(img + tid);
        const float s4 = (v.x + v.y) + (v.z + v.w);
        s_full = s4;
        if (tid < 32) s_top = s4;
        s_leftraw = v.x;                  // col-0 candidates: tid%32==0, all iters
        if (tid == 0) s_corner = v.x;
    }
    #pragma unroll
    for (int it = 1; it < 16; ++it) {
        fvec4 v = __builtin_nontemporal_load(img + tid + it * 256);
        s_full    += (v.x + v.y) + (v.z + v.w);
        s_leftraw += v.x;
    }
    float s_left = ((tid & 31) == 0) ? s_leftraw : 0.f;

    #pragma unroll
    for (int off = 32; off > 0; off >>= 1) {
        s_full   += __shfl_down(s_full, off);
        s_top    += __shfl_down(s_top, off);
        s_left   += __shfl_down(s_left, off);
        s_corner += __shfl_down(s_corner, off);
    }

    __shared__ float red[4][4];
    const int wave = tid >> 6, lane = tid & 63;
    if (lane == 0) {
        red[wave][0] = s_full;  red[wave][1] = s_top;
        red[wave][2] = s_left;  red[wave][3] = s_corner;
    }
    __syncthreads();
    if (tid < 4)
        stats[bc * 4 + tid] = (red[0][tid] + red[1][tid]) + (red[2][tid] + red[3][tid]);

    // ---- completion counter (stats stores happen-before the release RMW) ----
    __shared__ unsigned int s_done;
    __syncthreads();
    if (tid == 0)
        s_done = __hip_atomic_fetch_add(counter, 1u, __ATOMIC_ACQ_REL,
                                        __HIP_MEMORY_SCOPE_AGENT) + 1u;
    __syncthreads();
    const unsigned int done = s_done;             // block-uniform
    if (done <= (unsigned)(NBLK - NEPI)) return;  // not an epilogue block
    const int b = (int)done - (NBLK - NEPI) - 1;  // 0..63

    // ---- wait until all 4096 blocks published their stats ----
    if (tid == 0) {
        while (__hip_atomic_load(counter, __ATOMIC_ACQUIRE,
                                 __HIP_MEMORY_SCOPE_AGENT) < (unsigned)NBLK)
            __builtin_amdgcn_s_sleep(8);
    }
    __syncthreads();

    // ---- phase 2: out[b][*] ----
    __shared__ float st[256];                     // stats row b (64 c * 4)
    st[tid] = stats[b * 256 + tid];
    __syncthreads();

    const int o = tid & 127, h = tid >> 7;        // h = c-half
    float acc = 0.f;
    #pragma unroll 4
    for (int c = h * 32; c < h * 32 + 32; ++c) {
        const float* w = weight + ((size_t)c * 128 + o) * 9;
        const float w0=w[0], w1=w[1], w2=w[2], w3=w[3], w4=w[4],
                    w5=w[5], w6=w[6], w7=w[7], w8=w[8];
        const float cf = ((w0 + w1) + (w2 + w3)) + ((w4 + w5) + (w6 + w7)) + w8;
        const float ct = -((w0 + w1) + w2);
        const float cl = -((w0 + w3) + w6);
        acc += st[c*4+0]*cf + st[c*4+1]*ct + st[c*4+2]*cl + st[c*4+3]*w0;
    }
    __shared__ float part[2][128];
    part[h][o] = acc;
    __syncthreads();
    if (tid < 128)
        out[b * 128 + tid] = 2.0f * bias[tid]
                           + (part[0][tid] + part[1][tid]) * (2.0f / 65536.0f);
}

extern "C" void kernel_launch(void* const* d_in, const int* in_sizes, int n_in,
                              void* d_out, int out_size, void* d_ws, size_t ws_size,
                              hipStream_t stream) {
    const float* x      = (const float*)d_in[0];
    const float* weight = (const float*)d_in[1];
    const float* bias   = (const float*)d_in[2];
    float* out   = (float*)d_out;
    float* stats = (float*)d_ws;                              // 64 KiB
    unsigned int* counter = (unsigned int*)((char*)d_ws + 65536);

    (void)hipMemsetAsync(counter, 0, sizeof(unsigned int), stream); // graph memset node
    fused_kernel<<<NBLK, 256, 0, stream>>>(x, weight, bias, out, stats, counter);
}

// Round 4
// 198.248 us; speedup vs baseline: 1.3539x; 1.3539x over previous
//
#include <hip/hip_runtime.h>

// x: (64, 64, 128, 128) f32; weight: (64, 128, 3, 3) f32; bias: (128,) f32
// out: (64, 128, 1, 1) f32
// stats[b][c][j], j in {full, top(row0), left(col0), corner}
// out[b][o] = 2*bias[o] + (2/65536) * sum_{c,j} stats[b][c][j]*coeff[o][c][j]
//
// Single fused kernel: 4096 blocks compute stats; the last 64 blocks to
// finish (agent-scope atomic counter) each take one b-row, spin until all
// stats are published, and compute that row's 128 outputs.
// NOTE: no nontemporal loads — they collapsed VGPR use to 32 and serialized
// the 16-load chain (R3: 268us, 0.5 TB/s). Explicit reg-array restores MLP.

typedef float fvec4 __attribute__((ext_vector_type(4)));

static constexpr int NBLK = 4096;
static constexpr int NEPI = 64;   // epilogue blocks (one per b)

__global__ __launch_bounds__(256) void fused_kernel(const float* __restrict__ x,
                                                    const float* __restrict__ weight,
                                                    const float* __restrict__ bias,
                                                    float* __restrict__ out,
                                                    float* __restrict__ stats,
                                                    unsigned int* __restrict__ counter) {
    const int bc = blockIdx.x;            // b*64 + c
    const int tid = threadIdx.x;
    const fvec4* img = reinterpret_cast<const fvec4*>(x) + (size_t)bc * 4096;

    // ---- phase 1: load all 16 vectors first (maximize MLP), then reduce ----
    fvec4 v[16];
    #pragma unroll
    for (int it = 0; it < 16; ++it)
        v[it] = img[tid + it * 256];

    float s_full = 0.f, s_top = 0.f, s_leftraw = 0.f, s_corner = 0.f;
    #pragma unroll
    for (int it = 0; it < 16; ++it) {
        s_full    += (v[it].x + v[it].y) + (v[it].z + v[it].w);
        s_leftraw += v[it].x;             // col-0 candidate: only tid%32==0 keeps it
    }
    if (tid < 32) s_top = (v[0].x + v[0].y) + (v[0].z + v[0].w);  // row 0 = first 32 float4s
    if (tid == 0) s_corner = v[0].x;
    float s_left = ((tid & 31) == 0) ? s_leftraw : 0.f;

    #pragma unroll
    for (int off = 32; off > 0; off >>= 1) {
        s_full   += __shfl_down(s_full, off);
        s_top    += __shfl_down(s_top, off);
        s_left   += __shfl_down(s_left, off);
        s_corner += __shfl_down(s_corner, off);
    }

    __shared__ float red[4][4];
    const int wave = tid >> 6, lane = tid & 63;
    if (lane == 0) {
        red[wave][0] = s_full;  red[wave][1] = s_top;
        red[wave][2] = s_left;  red[wave][3] = s_corner;
    }
    __syncthreads();
    if (tid < 4)
        stats[bc * 4 + tid] = (red[0][tid] + red[1][tid]) + (red[2][tid] + red[3][tid]);

    // ---- completion counter (stats stores happen-before the release RMW) ----
    __shared__ unsigned int s_done;
    __syncthreads();
    if (tid == 0)
        s_done = __hip_atomic_fetch_add(counter, 1u, __ATOMIC_ACQ_REL,
                                        __HIP_MEMORY_SCOPE_AGENT) + 1u;
    __syncthreads();
    const unsigned int done = s_done;             // block-uniform
    if (done <= (unsigned)(NBLK - NEPI)) return;  // not an epilogue block
    const int b = (int)done - (NBLK - NEPI) - 1;  // 0..63

    // ---- wait until all 4096 blocks published their stats ----
    if (tid == 0) {
        while (__hip_atomic_load(counter, __ATOMIC_ACQUIRE,
                                 __HIP_MEMORY_SCOPE_AGENT) < (unsigned)NBLK)
            __builtin_amdgcn_s_sleep(8);
    }
    __syncthreads();

    // ---- phase 2: out[b][*] ----
    __shared__ float st[256];                     // stats row b (64 c * 4)
    st[tid] = stats[b * 256 + tid];
    __syncthreads();

    const int o = tid & 127, h = tid >> 7;        // h = c-half
    float acc = 0.f;
    #pragma unroll 4
    for (int c = h * 32; c < h * 32 + 32; ++c) {
        const float* w = weight + ((size_t)c * 128 + o) * 9;
        const float w0=w[0], w1=w[1], w2=w[2], w3=w[3], w4=w[4],
                    w5=w[5], w6=w[6], w7=w[7], w8=w[8];
        const float cf = ((w0 + w1) + (w2 + w3)) + ((w4 + w5) + (w6 + w7)) + w8;
        const float ct = -((w0 + w1) + w2);
        const float cl = -((w0 + w3) + w6);
        acc += st[c*4+0]*cf + st[c*4+1]*ct + st[c*4+2]*cl + st[c*4+3]*w0;
    }
    __shared__ float part[2][128];
    part[h][o] = acc;
    __syncthreads();
    if (tid < 128)
        out[b * 128 + tid] = 2.0f * bias[tid]
                           + (part[0][tid] + part[1][tid]) * (2.0f / 65536.0f);
}

extern "C" void kernel_launch(void* const* d_in, const int* in_sizes, int n_in,
                              void* d_out, int out_size, void* d_ws, size_t ws_size,
                              hipStream_t stream) {
    const float* x      = (const float*)d_in[0];
    const float* weight = (const float*)d_in[1];
    const float* bias   = (const float*)d_in[2];
    float* out   = (float*)d_out;
    float* stats = (float*)d_ws;                              // 64 KiB
    unsigned int* counter = (unsigned int*)((char*)d_ws + 65536);

    (void)hipMemsetAsync(counter, 0, sizeof(unsigned int), stream); // graph memset node
    fused_kernel<<<NBLK, 256, 0, stream>>>(x, weight, bias, out, stats, counter);
}

// Round 5
// 50.910 us; speedup vs baseline: 5.2722x; 3.8941x over previous
//
#include <hip/hip_runtime.h>

// x: (64, 64, 128, 128) f32; weight: (64, 128, 3, 3) f32; bias: (128,) f32
// out: (64, 128, 1, 1) f32
// stats[b][c][j], j in {full, top(row0), left(col0), corner}
// out[b][o] = 2*bias[o] + (2/65536) * sum_{c,j} stats[b][c][j]*coeff[o][c][j]
//
// Two kernels (R1 structure — proven 54us). R3/R4 post-mortem: fusing via an
// agent-scope acq_rel atomic per block emitted L2 writeback/invalidate cache
// maintenance that collapsed streaming BW to 0.5 TB/s. No cross-WG sync here.

typedef float fvec4 __attribute__((ext_vector_type(4)));

__global__ __launch_bounds__(256) void stats_kernel(const float* __restrict__ x,
                                                    float* __restrict__ stats) {
    const int bc = blockIdx.x;  // b*64 + c
    const int tid = threadIdx.x;
    const fvec4* img = reinterpret_cast<const fvec4*>(x) + (size_t)bc * 4096;

    float s_full = 0.f, s_top = 0.f, s_leftraw = 0.f, s_corner = 0.f;
    {   // iteration 0 contains row 0 (float4 index < 32)
        fvec4 v = img[tid];
        const float s4 = (v.x + v.y) + (v.z + v.w);
        s_full = s4;
        if (tid < 32) s_top = s4;
        s_leftraw = v.x;
        if (tid == 0) s_corner = v.x;
    }
    #pragma unroll
    for (int it = 1; it < 16; ++it) {
        fvec4 v = img[tid + it * 256];
        s_full    += (v.x + v.y) + (v.z + v.w);
        s_leftraw += v.x;                 // col-0 candidate; only lanes tid%32==0 keep it
    }
    float s_left = ((tid & 31) == 0) ? s_leftraw : 0.f;

    #pragma unroll
    for (int off = 32; off > 0; off >>= 1) {
        s_full   += __shfl_down(s_full, off);
        s_top    += __shfl_down(s_top, off);
        s_left   += __shfl_down(s_left, off);
        s_corner += __shfl_down(s_corner, off);
    }

    __shared__ float red[4][4];
    const int wave = tid >> 6, lane = tid & 63;
    if (lane == 0) {
        red[wave][0] = s_full;  red[wave][1] = s_top;
        red[wave][2] = s_left;  red[wave][3] = s_corner;
    }
    __syncthreads();
    if (tid < 4)
        stats[bc * 4 + tid] = (red[0][tid] + red[1][tid]) + (red[2][tid] + red[3][tid]);
}

__global__ __launch_bounds__(256) void out_kernel(const float* __restrict__ stats,
                                                  const float* __restrict__ weight,
                                                  const float* __restrict__ bias,
                                                  float* __restrict__ out) {
    const int b = blockIdx.x;             // 0..63
    const int tid = threadIdx.x;
    const int o = tid & 127, h = tid >> 7;  // h = c-half

    __shared__ float st[256];             // stats row b (64 c * 4)
    st[tid] = stats[b * 256 + tid];
    __syncthreads();

    float acc = 0.f;
    #pragma unroll 4
    for (int c = h * 32; c < h * 32 + 32; ++c) {
        const float* w = weight + ((size_t)c * 128 + o) * 9;
        const float w0=w[0], w1=w[1], w2=w[2], w3=w[3], w4=w[4],
                    w5=w[5], w6=w[6], w7=w[7], w8=w[8];
        const float cf = ((w0 + w1) + (w2 + w3)) + ((w4 + w5) + (w6 + w7)) + w8;
        const float ct = -((w0 + w1) + w2);
        const float cl = -((w0 + w3) + w6);
        acc += st[c*4+0]*cf + st[c*4+1]*ct + st[c*4+2]*cl + st[c*4+3]*w0;
    }
    __shared__ float part[2][128];
    part[h][o] = acc;
    __syncthreads();
    if (tid < 128)
        out[b * 128 + tid] = 2.0f * bias[tid]
                           + (part[0][tid] + part[1][tid]) * (2.0f / 65536.0f);
}

extern "C" void kernel_launch(void* const* d_in, const int* in_sizes, int n_in,
                              void* d_out, int out_size, void* d_ws, size_t ws_size,
                              hipStream_t stream) {
    const float* x      = (const float*)d_in[0];
    const float* weight = (const float*)d_in[1];
    const float* bias   = (const float*)d_in[2];
    float* out   = (float*)d_out;
    float* stats = (float*)d_ws;          // 64*64*4 floats = 64 KiB < ws

    stats_kernel<<<4096, 256, 0, stream>>>(x, stats);
    out_kernel<<<64, 256, 0, stream>>>(stats, weight, bias, out);
}

// Round 6
// 50.748 us; speedup vs baseline: 5.2890x; 1.0032x over previous
//
#include <hip/hip_runtime.h>

// x: (64, 64, 128, 128) f32; weight: (64, 128, 3, 3) f32; bias: (128,) f32
// out: (64, 128, 1, 1) f32
// stats[b][c][j], j in {full, top(row0), left(col0), corner}
// out[b][o] = 2*bias[o] + (2/65536) * sum_{c,j} stats[b][c][j]*coeff[o][c][j]
//
// Two kernels. R3/R4 post-mortem: per-block agent-scope acq_rel atomics emit
// L2 cache maintenance -> 0.5 TB/s; never fuse via cross-WG sync here.
// R6: wave-contiguous streaming (each wave reads a contiguous 16 KiB quarter)
// for DRAM row-buffer locality; 512-thread epilogue.

typedef float fvec4 __attribute__((ext_vector_type(4)));

__global__ __launch_bounds__(256) void stats_kernel(const float* __restrict__ x,
                                                    float* __restrict__ stats) {
    const int bc = blockIdx.x;  // b*64 + c
    const int tid = threadIdx.x;
    const int wave = tid >> 6, lane = tid & 63;
    const fvec4* img = reinterpret_cast<const fvec4*>(x) + (size_t)bc * 4096;

    // each wave streams a contiguous 16 KiB quarter: idx = wave*1024 + it*64 + lane
    float s_full = 0.f, s_top = 0.f, s_leftraw = 0.f, s_corner = 0.f;
    #pragma unroll
    for (int it = 0; it < 16; ++it) {
        const int idx = wave * 1024 + it * 64 + lane;   // float4 index
        fvec4 v = img[idx];
        const float s4 = (v.x + v.y) + (v.z + v.w);
        s_full += s4;
        if (idx < 32) s_top += s4;        // row 0 = float4 indices 0..31 (wave 0, it 0)
        s_leftraw += v.x;                 // col-0 candidate; lanes 0,32 only (masked below)
        if (idx == 0) s_corner = v.x;
    }
    float s_left = ((lane & 31) == 0) ? s_leftraw : 0.f;

    #pragma unroll
    for (int off = 32; off > 0; off >>= 1) {
        s_full   += __shfl_down(s_full, off);
        s_top    += __shfl_down(s_top, off);
        s_left   += __shfl_down(s_left, off);
        s_corner += __shfl_down(s_corner, off);
    }

    __shared__ float red[4][4];
    if (lane == 0) {
        red[wave][0] = s_full;  red[wave][1] = s_top;
        red[wave][2] = s_left;  red[wave][3] = s_corner;
    }
    __syncthreads();
    if (tid < 4)
        stats[bc * 4 + tid] = (red[0][tid] + red[1][tid]) + (red[2][tid] + red[3][tid]);
}

__global__ __launch_bounds__(512) void out_kernel(const float* __restrict__ stats,
                                                  const float* __restrict__ weight,
                                                  const float* __restrict__ bias,
                                                  float* __restrict__ out) {
    const int b = blockIdx.x;               // 0..63
    const int tid = threadIdx.x;
    const int o = tid & 127, q = tid >> 7;  // q = c-quarter (0..3)

    __shared__ float st[256];               // stats row b (64 c * 4)
    if (tid < 256) st[tid] = stats[b * 256 + tid];
    __syncthreads();

    float acc = 0.f;
    #pragma unroll 4
    for (int c = q * 16; c < q * 16 + 16; ++c) {
        const float* w = weight + ((size_t)c * 128 + o) * 9;
        const float w0=w[0], w1=w[1], w2=w[2], w3=w[3], w4=w[4],
                    w5=w[5], w6=w[6], w7=w[7], w8=w[8];
        const float cf = ((w0 + w1) + (w2 + w3)) + ((w4 + w5) + (w6 + w7)) + w8;
        const float ct = -((w0 + w1) + w2);
        const float cl = -((w0 + w3) + w6);
        acc += st[c*4+0]*cf + st[c*4+1]*ct + st[c*4+2]*cl + st[c*4+3]*w0;
    }
    __shared__ float part[4][128];
    part[q][o] = acc;
    __syncthreads();
    if (tid < 128)
        out[b * 128 + tid] = 2.0f * bias[tid]
                           + ((part[0][tid] + part[1][tid]) + (part[2][tid] + part[3][tid]))
                             * (2.0f / 65536.0f);
}

extern "C" void kernel_launch(void* const* d_in, const int* in_sizes, int n_in,
                              void* d_out, int out_size, void* d_ws, size_t ws_size,
                              hipStream_t stream) {
    const float* x      = (const float*)d_in[0];
    const float* weight = (const float*)d_in[1];
    const float* bias   = (const float*)d_in[2];
    float* out   = (float*)d_out;
    float* stats = (float*)d_ws;            // 64*64*4 floats = 64 KiB < ws

    stats_kernel<<<4096, 256, 0, stream>>>(x, stats);
    out_kernel<<<64, 512, 0, stream>>>(stats, weight, bias, out);
}

// Round 7
// 48.710 us; speedup vs baseline: 5.5104x; 1.0418x over previous
//
#include <hip/hip_runtime.h>

// x: (64, 64, 128, 128) f32; weight: (64, 128, 3, 3) f32; bias: (128,) f32
// out: (64, 128, 1, 1) f32
// out[b][o] = 2*bias[o] + (2/65536) * sum_c [ s_full*cf + s_top*ct + s_left*cl + s_corner*w00 ]
//   cf = sum_kl w[c][o]; ct = -sum_l w[c][o][0][l]; cl = -sum_k w[c][o][k][0]; w00 = w[c][o][0][0]
//
// Single streaming kernel, one block per (b,c) image. After the in-block
// reduction, 128 threads fold this block's contribution into out via RELAXED
// hw fp32 atomics (global_atomic_add_f32 — no fence, no L2 cache maintenance;
// R3/R4 showed acq_rel agent-scope ordering is what collapses BW to 0.5 TB/s).
// out is re-zeroed every call by a graph-captured memset node.

typedef float fvec4 __attribute__((ext_vector_type(4)));

__global__ __launch_bounds__(256) void fused_stats_kernel(const float* __restrict__ x,
                                                          const float* __restrict__ weight,
                                                          const float* __restrict__ bias,
                                                          float* __restrict__ out) {
    const int bc = blockIdx.x;            // b*64 + c
    const int b = bc >> 6, c = bc & 63;
    const int tid = threadIdx.x;
    const int wave = tid >> 6, lane = tid & 63;
    const fvec4* img = reinterpret_cast<const fvec4*>(x) + (size_t)bc * 4096;

    // each wave streams a contiguous 16 KiB quarter of the image
    float s_full = 0.f, s_top = 0.f, s_leftraw = 0.f, s_corner = 0.f;
    #pragma unroll
    for (int it = 0; it < 16; ++it) {
        const int idx = wave * 1024 + it * 64 + lane;   // float4 index
        fvec4 v = img[idx];
        const float s4 = (v.x + v.y) + (v.z + v.w);
        s_full += s4;
        if (idx < 32) s_top += s4;        // row 0 = float4 indices 0..31
        s_leftraw += v.x;                 // col-0 candidate (lanes with idx%32==0)
        if (idx == 0) s_corner = v.x;
    }
    float s_left = ((lane & 31) == 0) ? s_leftraw : 0.f;

    #pragma unroll
    for (int off = 32; off > 0; off >>= 1) {
        s_full   += __shfl_down(s_full, off);
        s_top    += __shfl_down(s_top, off);
        s_left   += __shfl_down(s_left, off);
        s_corner += __shfl_down(s_corner, off);
    }

    __shared__ float red[4][4];
    __shared__ float st[4];
    if (lane == 0) {
        red[wave][0] = s_full;  red[wave][1] = s_top;
        red[wave][2] = s_left;  red[wave][3] = s_corner;
    }
    __syncthreads();
    if (tid < 4)
        st[tid] = (red[0][tid] + red[1][tid]) + (red[2][tid] + red[3][tid]);
    __syncthreads();

    // fold this (b,c) block's contribution into out[b][*]
    if (tid < 128) {
        const int o = tid;
        const float* w = weight + ((size_t)c * 128 + o) * 9;   // L2-hot (288 KB total)
        const float w0=w[0], w1=w[1], w2=w[2], w3=w[3], w4=w[4],
                    w5=w[5], w6=w[6], w7=w[7], w8=w[8];
        const float cf = ((w0 + w1) + (w2 + w3)) + ((w4 + w5) + (w6 + w7)) + w8;
        const float ct = -((w0 + w1) + w2);
        const float cl = -((w0 + w3) + w6);
        float contrib = (st[0]*cf + st[1]*ct + st[2]*cl + st[3]*w0) * (2.0f / 65536.0f);
        if (c == 0) contrib += 2.0f * bias[o];
        unsafeAtomicAdd(&out[b * 128 + o], contrib);   // relaxed hw fp32 atomic
    }
}

extern "C" void kernel_launch(void* const* d_in, const int* in_sizes, int n_in,
                              void* d_out, int out_size, void* d_ws, size_t ws_size,
                              hipStream_t stream) {
    const float* x      = (const float*)d_in[0];
    const float* weight = (const float*)d_in[1];
    const float* bias   = (const float*)d_in[2];
    float* out = (float*)d_out;

    (void)hipMemsetAsync(out, 0, (size_t)out_size * sizeof(float), stream); // graph memset node
    fused_stats_kernel<<<4096, 256, 0, stream>>>(x, weight, bias, out);
}